// Round 3
// baseline (436.891 us; speedup 1.0000x reference)
//
#include <hip/hip_runtime.h>
#include <math.h>

#define B_ROWS 512
#define D_DIM  512
#define C_CLS  100000
#define SCALE  64.0f
#define EPSN   1e-12f

#define BM 128
#define BN 128
#define BK 64
#define KT (D_DIM / BK)      // 8 K-iterations
#define NTILE 782            // ceil(100000/128)
#define NT2   (NTILE*2)      // partials per row (one per 64-col wave slice)
#define NBLK  (4 * NTILE)    // 3128
#define SLOTS (NBLK / 8)     // 391 per XCD

typedef __attribute__((ext_vector_type(8))) short bf16x8;
typedef __attribute__((ext_vector_type(4))) float f32x4;

__device__ inline unsigned short f2bf(float f) {
    union { float f; unsigned int u; } v; v.f = f;
    unsigned int r = v.u + 0x7fffu + ((v.u >> 16) & 1u);
    return (unsigned short)(r >> 16);
}
__device__ inline float bf2f(unsigned short h) {
    union { unsigned int u; float f; } v; v.u = ((unsigned int)h) << 16;
    return v.f;
}

// ---------- normalize x rows, store bf16 ----------
__global__ void normalize_x(const float* __restrict__ x, unsigned short* __restrict__ xnb) {
    int row  = blockIdx.x;
    int lane = threadIdx.x;  // 64
    const float4* xr = (const float4*)(x + (size_t)row * D_DIM);
    float4 a = xr[lane];
    float4 b = xr[lane + 64];
    float ss = a.x*a.x + a.y*a.y + a.z*a.z + a.w*a.w
             + b.x*b.x + b.y*b.y + b.z*b.z + b.w*b.w;
    #pragma unroll
    for (int m = 1; m < 64; m <<= 1) ss += __shfl_xor(ss, m);
    float inv = 1.0f / fmaxf(sqrtf(ss), EPSN);
    ushort4 o0, o1;
    o0.x = f2bf(a.x*inv); o0.y = f2bf(a.y*inv); o0.z = f2bf(a.z*inv); o0.w = f2bf(a.w*inv);
    o1.x = f2bf(b.x*inv); o1.y = f2bf(b.y*inv); o1.z = f2bf(b.z*inv); o1.w = f2bf(b.w*inv);
    ushort4* orow = (ushort4*)(xnb + (size_t)row * D_DIM);
    orow[lane]      = o0;
    orow[lane + 64] = o1;
}

// ---------- W prep: wn[c,:] = w[c,:] * S / ||w[c,:]||, bf16 ----------
__global__ void w_prep(const float* __restrict__ w, unsigned short* __restrict__ wn) {
    int c    = blockIdx.x * 4 + (threadIdx.x >> 6);
    int lane = threadIdx.x & 63;
    const float4* wr = (const float4*)(w + (size_t)c * D_DIM);
    float4 a = wr[lane];
    float4 b = wr[lane + 64];
    float ss = a.x*a.x + a.y*a.y + a.z*a.z + a.w*a.w
             + b.x*b.x + b.y*b.y + b.z*b.z + b.w*b.w;
    #pragma unroll
    for (int m = 1; m < 64; m <<= 1) ss += __shfl_xor(ss, m);
    float s = SCALE / fmaxf(sqrtf(ss), EPSN);
    ushort4 o0, o1;
    o0.x = f2bf(a.x*s); o0.y = f2bf(a.y*s); o0.z = f2bf(a.z*s); o0.w = f2bf(a.w*s);
    o1.x = f2bf(b.x*s); o1.y = f2bf(b.y*s); o1.z = f2bf(b.z*s); o1.w = f2bf(b.w*s);
    ushort4* orow = (ushort4*)(wn + (size_t)c * D_DIM);
    orow[lane]      = o0;
    orow[lane + 64] = o1;
}

// ---------- bf16 MFMA GEMM, BK=64, XCD-swizzled, bank-conflict-free ----------
// LDS layout: tile row r (0..127) holds 8 16B-chunks; LDS slot s within the row
// stores GLOBAL k-chunk (s ^ (r&7)). Staged via global_load_lds with dest
// base + lane*16 (slot index == linear chunk id), global address carries the xor.
__global__ __launch_bounds__(256) void gemm_ce(const unsigned short* __restrict__ xnb,
                                               const unsigned short* __restrict__ wn,
                                               float2* __restrict__ partials) {
    __shared__ unsigned short As[BM * BK];  // 16 KB
    __shared__ unsigned short Bs[BN * BK];  // 16 KB

    int tid  = threadIdx.x;
    int bid  = blockIdx.x;
    // XCD-aware remap: each XCD gets a contiguous work range -> W L2 locality
    int xcd  = bid & 7;
    int slot = bid >> 3;
    int wk   = xcd * SLOTS + slot;       // 0..3127
    int m0   = (wk & 3) * BM;
    int ct   = wk >> 2;                  // 0..781
    int c0   = ct * BN;

    int wid  = tid >> 6;
    int lane = tid & 63;
    int quad = lane >> 4;
    int lr   = lane & 15;
    int wr   = wid >> 1;
    int wc   = wid & 1;

    f32x4 acc[4][4];
    #pragma unroll
    for (int i = 0; i < 4; i++)
        #pragma unroll
        for (int j = 0; j < 4; j++) {
            acc[i][j][0] = 0.f; acc[i][j][1] = 0.f; acc[i][j][2] = 0.f; acc[i][j][3] = 0.f;
        }

    // staging precompute: pass p stages chunk c = p*256+tid; row=c>>3, cc=c&7,
    // global k-chunk = cc ^ (row&7); LDS slot = c (so dest = wavebase + lane*16)
    int arow[4], koff[4], brow[4];
    #pragma unroll
    for (int p = 0; p < 4; p++) {
        int c   = p * 256 + tid;
        int r   = c >> 3;
        koff[p] = ((c & 7) ^ (r & 7)) * 8;   // ushort offset within the 64-k tile
        arow[p] = m0 + r;
        int bc  = c0 + r; if (bc >= C_CLS) bc = C_CLS - 1;
        brow[p] = bc;
    }

    for (int kt = 0; kt < KT; ++kt) {
        int k0 = kt * BK;
        __syncthreads();
        #pragma unroll
        for (int p = 0; p < 4; p++) {
            unsigned short* adst = As + (p * 256 + wid * 64) * 8;  // +lane*16B implicit
            unsigned short* bdst = Bs + (p * 256 + wid * 64) * 8;
            __builtin_amdgcn_global_load_lds(
                (const __attribute__((address_space(1))) void*)(xnb + (size_t)arow[p] * D_DIM + k0 + koff[p]),
                (__attribute__((address_space(3))) void*)adst, 16, 0, 0);
            __builtin_amdgcn_global_load_lds(
                (const __attribute__((address_space(1))) void*)(wn + (size_t)brow[p] * D_DIM + k0 + koff[p]),
                (__attribute__((address_space(3))) void*)bdst, 16, 0, 0);
        }
        __syncthreads();

        #pragma unroll
        for (int ks = 0; ks < 2; ks++) {
            bf16x8 af[4], bf[4];
            #pragma unroll
            for (int i = 0; i < 4; i++) {
                int r = wr * 64 + i * 16 + lr;
                af[i] = *(const bf16x8*)(As + r * BK + (((ks * 4 + quad) ^ (r & 7)) * 8));
            }
            #pragma unroll
            for (int j = 0; j < 4; j++) {
                int r = wc * 64 + j * 16 + lr;
                bf[j] = *(const bf16x8*)(Bs + r * BK + (((ks * 4 + quad) ^ (r & 7)) * 8));
            }
            #pragma unroll
            for (int i = 0; i < 4; i++)
                #pragma unroll
                for (int j = 0; j < 4; j++)
                    acc[i][j] = __builtin_amdgcn_mfma_f32_16x16x32_bf16(af[i], bf[j], acc[i][j], 0, 0, 0);
        }
    }

    // epilogue: per-row online-softmax partial over this wave's 64 cols
    int valid[4];
    #pragma unroll
    for (int j = 0; j < 4; j++)
        valid[j] = (c0 + wc * 64 + j * 16 + lr) < C_CLS;
    int tile2 = ct * 2 + wc;
    #pragma unroll
    for (int i = 0; i < 4; i++) {
        #pragma unroll
        for (int r = 0; r < 4; r++) {
            int row_g = m0 + wr * 64 + i * 16 + quad * 4 + r;
            float v0 = valid[0] ? acc[i][0][r] : -1e30f;
            float v1 = valid[1] ? acc[i][1][r] : -1e30f;
            float v2 = valid[2] ? acc[i][2][r] : -1e30f;
            float v3 = valid[3] ? acc[i][3][r] : -1e30f;
            float m = fmaxf(fmaxf(v0, v1), fmaxf(v2, v3));
            #pragma unroll
            for (int msk = 1; msk < 16; msk <<= 1) m = fmaxf(m, __shfl_xor(m, msk));
            float s = expf(v0 - m) + expf(v1 - m) + expf(v2 - m) + expf(v3 - m);
            #pragma unroll
            for (int msk = 1; msk < 16; msk <<= 1) s += __shfl_xor(s, msk);
            if (lr == 0)
                partials[(size_t)row_g * NT2 + tile2] = make_float2(m, s);
        }
    }
}

// ---------- fused: label logit + merge partials -> LSE -> mean NLL ----------
__global__ void reduce_loss(const float2* __restrict__ partials,
                            const unsigned short* __restrict__ xnb,
                            const unsigned short* __restrict__ wn,
                            const int* __restrict__ label,
                            float* __restrict__ out) {
    __shared__ float sm[256], ssum[256], sdot[256];
    int row = blockIdx.x, tid = threadIdx.x;

    // label-logit partial: 128 threads x ushort4 covers D=512
    float d = 0.f;
    int lab = label[row];
    if (tid < 128) {
        ushort4 xv = ((const ushort4*)(xnb + (size_t)row * D_DIM))[tid];
        ushort4 wv = ((const ushort4*)(wn + (size_t)lab * D_DIM))[tid];
        d = bf2f(xv.x) * bf2f(wv.x) + bf2f(xv.y) * bf2f(wv.y)
          + bf2f(xv.z) * bf2f(wv.z) + bf2f(xv.w) * bf2f(wv.w);
    }
    sdot[tid] = d;

    // online merge of this row's 1564 partials
    float m = -INFINITY, s = 0.f;
    for (int idx = tid; idx < NT2; idx += 256) {
        float2 p = partials[(size_t)row * NT2 + idx];
        if (p.x > m) { s = s * expf(m - p.x) + p.y; m = p.x; }
        else         { s += p.y * expf(p.x - m); }
    }
    sm[tid] = m; ssum[tid] = s;
    __syncthreads();
    for (int off = 128; off > 0; off >>= 1) {
        if (tid < off) {
            float m2 = sm[tid + off], s2 = ssum[tid + off];
            float mm = fmaxf(m, m2);
            s = s * expf(m - mm) + s2 * expf(m2 - mm);
            m = mm;
            sm[tid] = m; ssum[tid] = s;
            sdot[tid] += sdot[tid + off];
        }
        __syncthreads();
    }
    if (tid == 0) {
        float lse = m + logf(s);
        atomicAdd(out, (lse - sdot[0]) * (1.0f / (float)B_ROWS));
    }
}

extern "C" void kernel_launch(void* const* d_in, const int* in_sizes, int n_in,
                              void* d_out, int out_size, void* d_ws, size_t ws_size,
                              hipStream_t stream) {
    const float* x     = (const float*)d_in[0];
    const float* w     = (const float*)d_in[1];
    const int*   label = (const int*)d_in[2];
    float* out = (float*)d_out;

    char* ws = (char*)d_ws;
    unsigned short* xnb = (unsigned short*)ws;                 // 524288 B
    float2* partials    = (float2*)(ws + 524288);              // 6406144 B (ends 6930432)
    unsigned short* wn  = (unsigned short*)(ws + 6930432);     // 102400000 B (ends 109330432)

    hipMemsetAsync(d_out, 0, sizeof(float), stream);
    normalize_x<<<B_ROWS, 64, 0, stream>>>(x, xnb);
    w_prep<<<C_CLS / 4, 256, 0, stream>>>(w, wn);
    gemm_ce<<<NBLK, 256, 0, stream>>>(xnb, wn, partials);
    reduce_loss<<<B_ROWS, 256, 0, stream>>>(partials, xnb, wn, label, out);
}